// Round 12
// baseline (168.239 us; speedup 1.0000x reference)
//
#include <hip/hip_runtime.h>
#include <math.h>

// Problem constants
#define HH 512
#define WW 512
#define NB 64
#define CXY 56          // crop offset of Xc in x
#define TOFF 66         // crop offset of tmpl in template (MS+C = 10+56)
#define TN 380          // template side
#define XN 400          // cropped image side
#define NL 21           // number of lags per dim (XN-TN+1)
#define N_T 144400.0f   // TN*TN
#define EPSF 1e-8f
#define NUT 32          // u-tiles of 12 owned rows (32*12 = 384 >= 380)
#define SXS 424         // padded sX row stride in halfs (848 B)

// d_ws float offsets.  NOTE: CCPART2 aliases ROWSUM/ROWSUMSQ (dead after k_vert).
#define TPART_S   0                    // 380
#define TPART_S2  384                  // 380
#define TSTATS    768                  // [0]=mu_t [1]=t_var
#define ROWSUM    1024                 // 64*400*21 = 537600
#define ROWSUMSQ  (ROWSUM + 537600)    // 538624 (end 1076224)
#define CCPART2   1024                 // alias: 64*32*441 = 903168 (end 904192, fits)
#define LOCALSUM  1076224              // 64*441
#define LOCALSQ   (LOCALSUM + 28224)   // 1104448 (end 1132672)
#define SHIFTS    1132672              // final float shifts (128)
#define SHIFTSI   (SHIFTS + 128)       // integer argmax cells (128)
#define EXACTN    (SHIFTSI + 128)      // (unused, kept for layout stability)
#define TSHIFT_F  (EXACTN + 384)       // 1133312; f16 21*384*416 halfs (1677312 floats)
#define XF16      (TSHIFT_F + 1677312) // 2810624; f16 Xc 64*416*416 halfs (5537792 floats)
// end: 8348416 floats = 33.4 MB

typedef _Float16 half2_t __attribute__((ext_vector_type(2)));
typedef _Float16 f16x8 __attribute__((ext_vector_type(8)));
typedef float f32x4 __attribute__((ext_vector_type(4)));

// ---------------- K0a: per-template-row partial sums ----------------
__global__ __launch_bounds__(128) void k_tstats1(const float* __restrict__ tpl,
                                                 float* __restrict__ ws) {
    int u = blockIdx.x;            // 0..379
    int l = threadIdx.x;           // 128
    const float* row = tpl + (TOFF + u) * WW + TOFF;
    float s = 0.f, s2 = 0.f;
    for (int v = l; v < TN; v += 128) { float t = row[v]; s += t; s2 += t * t; }
    for (int off = 32; off; off >>= 1) { s += __shfl_down(s, off); s2 += __shfl_down(s2, off); }
    __shared__ float rs[2], rs2[2];
    int wid = l >> 6;
    if ((l & 63) == 0) { rs[wid] = s; rs2[wid] = s2; }
    __syncthreads();
    if (l == 0) { ws[TPART_S + u] = rs[0] + rs[1]; ws[TPART_S2 + u] = rs2[0] + rs2[1]; }
}

// ---------------- K0b: finalize template stats ----------------
__global__ __launch_bounds__(512) void k_tstats2(float* __restrict__ ws) {
    int l = threadIdx.x;           // 512
    float s  = (l < TN) ? ws[TPART_S + l]  : 0.f;
    float s2 = (l < TN) ? ws[TPART_S2 + l] : 0.f;
    for (int off = 32; off; off >>= 1) { s += __shfl_down(s, off); s2 += __shfl_down(s2, off); }
    __shared__ float rs[8], rs2[8];
    int wid = l >> 6;
    if ((l & 63) == 0) { rs[wid] = s; rs2[wid] = s2; }
    __syncthreads();
    if (l == 0) {
        float S = 0.f, S2 = 0.f;
        for (int k = 0; k < 8; ++k) { S += rs[k]; S2 += rs2[k]; }
        float mu = S / N_T;
        ws[TSTATS] = mu;
        ws[TSTATS + 1] = S2 - S * mu + EPSF;   // sum((T-mu)^2) + EPS
    }
}

// ---------------- K0c: build 21 shifted zero-mean f16 template copies ----------------
__global__ __launch_bounds__(256) void k_tshift(const float* __restrict__ tpl,
                                                float* __restrict__ ws) {
    int u = blockIdx.x;            // 0..383
    int j = blockIdx.y;            // 0..20
    float mu = ws[TSTATS];
    _Float16* dst = (_Float16*)(ws + TSHIFT_F) + ((size_t)j * 384 + u) * 416;
    for (int c = threadIdx.x; c < 416; c += 256) {
        float v = 0.f;
        int vs = c - j;
        if (u < TN && vs >= 0 && vs < TN) v = tpl[(TOFF + u) * WW + TOFF + vs] - mu;
        dst[c] = (_Float16)v;
    }
}

// ---------------- K1: sliding window sums + fused f32->f16 conversion ----------------
__global__ __launch_bounds__(256) void k_rowsum(const float* __restrict__ x,
                                                float* __restrict__ ws) {
    __shared__ float sm[4][416];
    int wid = threadIdx.x >> 6, lane = threadIdx.x & 63;
    int row = blockIdx.x * 4 + wid;        // 0..26623
    int b = row / 416, p = row - b * 416;  // p in [0,416)
    const float* xr = x + ((size_t)b * HH + (CXY + p)) * WW + CXY;
    _Float16* xh = (_Float16*)(ws + XF16) + ((size_t)b * 416 + p) * 416;
    float s = 0.f, s2 = 0.f;
    for (int v = lane; v < 416; v += 64) {
        float t = xr[v];
        sm[wid][v] = t;
        xh[v] = (_Float16)t;
        if (v < TN) { s += t; s2 += t * t; }
    }
    for (int off = 32; off; off >>= 1) { s += __shfl_down(s, off); s2 += __shfl_down(s2, off); }
    __syncthreads();
    if (lane == 0 && p < XN) {
        float* rs  = ws + ROWSUM   + (size_t)(b * XN + p) * NL;
        float* rq  = ws + ROWSUMSQ + (size_t)(b * XN + p) * NL;
        float w = s, w2 = s2;
        rs[0] = w; rq[0] = w2;
        for (int j = 1; j < NL; ++j) {
            float a = sm[wid][j - 1], bv = sm[wid][j + TN - 1];
            w  += bv - a;
            w2 += bv * bv - a * a;
            rs[j] = w; rq[j] = w2;
        }
    }
}

// ---------------- K2: vertical 380-tall sums (split sum/sumsq, padded LDS) ----------------
__global__ __launch_bounds__(512) void k_vert(float* __restrict__ ws) {
    int b = blockIdx.x, half = blockIdx.y, t = threadIdx.x;
    __shared__ float sm[XN * 22];   // padded stride 22 (2-way max)
    const float* src = ws + (half ? ROWSUMSQ : ROWSUM) + (size_t)b * (XN * NL);
    for (int k = t; k < XN * NL; k += 512) {
        int p = k / NL, j = k - p * NL;
        sm[p * 22 + j] = src[k];
    }
    __syncthreads();
    if (t < NL * NL) {
        int i = t / NL, j = t - i * NL;
        const float* base = sm + i * 22 + j;
        float s0 = 0.f, s1 = 0.f, s2 = 0.f, s3 = 0.f;
        for (int p = 0; p < TN; p += 4) {
            s0 += base[p * 22];
            s1 += base[(p + 1) * 22];
            s2 += base[(p + 2) * 22];
            s3 += base[(p + 3) * 22];
        }
        ws[(half ? LOCALSQ : LOCALSUM) + b * (NL * NL) + t] = (s0 + s1) + (s2 + s3);
    }
}

// ---------------- K3: MFMA cross-correlation (12-u tiles, 3-j groups, ring-2) ----------------
// FROZEN at round-10 best: 49.0 us, VGPR 52, no spill.
__global__ __launch_bounds__(256) void k_ccm(float* __restrict__ ws) {
    const int b = blockIdx.x, ut = blockIdx.y;   // b fastest: concurrent blocks share A-tile
    const int U = 12 * ut;
    const int tid = threadIdx.x;
    const int lane = tid & 63, wv = tid >> 6;
    __shared__ __align__(16) _Float16 sX[32 * SXS];   // 27136 B
    __shared__ float sD[4][16][34];                   // 8704 B -> 35840 total, 4 blocks/CU

    // ---- stage 32 rows x 416 halfs from xh (16B chunks, coalesced) ----
    {
        const _Float16* src0 = (const _Float16*)(ws + XF16)
                             + ((size_t)b * 416 + U) * 416;
        for (int c = tid; c < 32 * 52; c += 256) {
            int r = c / 52, c8 = c - r * 52;
            *reinterpret_cast<f16x8*>(sX + r * SXS + c8 * 8) =
                *reinterpret_cast<const f16x8*>(src0 + (size_t)r * 416 + c8 * 8);
        }
    }
    __syncthreads();

    const _Float16* tsh = (const _Float16*)(ws + TSHIFT_F);
    const int r16 = lane & 15, h8 = (lane >> 4) * 8;
    const int rbase = (lane >> 4) * 4, cbase = lane & 15;
    const _Float16* bb0 = sX + r16 * SXS + h8;

    for (int gi = 0; gi < 2; ++gi) {
        const int g = wv + 4 * gi;
        if (g >= 7) break;                    // wave-uniform
        const int j0 = 3 * g;                 // j0, j0+1, j0+2 (7*3 = 21 exactly)
        const _Float16* a0 = tsh + ((size_t)(j0    ) * 384 + U + r16) * 416 + h8;
        const _Float16* a1 = tsh + ((size_t)(j0 + 1) * 384 + U + r16) * 416 + h8;
        const _Float16* a2 = tsh + ((size_t)(j0 + 2) * 384 + U + r16) * 416 + h8;

        f32x4 c00 = {0.f, 0.f, 0.f, 0.f};
        f32x4 c01 = c00, c10 = c00, c11 = c00, c20 = c00, c21 = c00;
        f16x8 A0 = *reinterpret_cast<const f16x8*>(a0);
        f16x8 A1 = *reinterpret_cast<const f16x8*>(a1);
        f16x8 A2 = *reinterpret_cast<const f16x8*>(a2);
#pragma unroll
        for (int kc = 0; kc < 13; ++kc) {
            f16x8 N0 = A0, N1 = A1, N2 = A2;
            if (kc < 12) {
                N0 = *reinterpret_cast<const f16x8*>(a0 + (kc + 1) * 32);
                N1 = *reinterpret_cast<const f16x8*>(a1 + (kc + 1) * 32);
                N2 = *reinterpret_cast<const f16x8*>(a2 + (kc + 1) * 32);
            }
            f16x8 B0 = *reinterpret_cast<const f16x8*>(bb0 + kc * 32);
            f16x8 B1 = *reinterpret_cast<const f16x8*>(bb0 + 16 * SXS + kc * 32);
            __builtin_amdgcn_s_setprio(1);
            c00 = __builtin_amdgcn_mfma_f32_16x16x32_f16(A0, B0, c00, 0, 0, 0);
            c01 = __builtin_amdgcn_mfma_f32_16x16x32_f16(A0, B1, c01, 0, 0, 0);
            c10 = __builtin_amdgcn_mfma_f32_16x16x32_f16(A1, B0, c10, 0, 0, 0);
            c11 = __builtin_amdgcn_mfma_f32_16x16x32_f16(A1, B1, c11, 0, 0, 0);
            c20 = __builtin_amdgcn_mfma_f32_16x16x32_f16(A2, B0, c20, 0, 0, 0);
            c21 = __builtin_amdgcn_mfma_f32_16x16x32_f16(A2, B1, c21, 0, 0, 0);
            __builtin_amdgcn_s_setprio(0);
            A0 = N0; A1 = N1; A2 = N2;
        }

        // ---- extract per j: s_i = sum_{row<12} D[row][row+i] (per-wave sD) ----
#pragma unroll
        for (int jj = 0; jj < 3; ++jj) {
            f32x4 d0 = (jj == 0) ? c00 : (jj == 1) ? c10 : c20;
            f32x4 d1 = (jj == 0) ? c01 : (jj == 1) ? c11 : c21;
#pragma unroll
            for (int q = 0; q < 4; ++q) {
                sD[wv][rbase + q][cbase]      = d0[q];
                sD[wv][rbase + q][16 + cbase] = d1[q];
            }
            if (lane < NL) {
                float s = 0.f;
#pragma unroll
                for (int row = 0; row < 12; ++row) s += sD[wv][row][row + lane];
                ws[CCPART2 + ((size_t)(b * NUT + ut)) * 441 + lane * NL + (j0 + jj)] = s;
            }
        }
    }
}

// ---------------- K4: NCC + argmax (first-index ties) -> integer cell ----------------
__global__ __launch_bounds__(512) void k_ncc(float* __restrict__ ws) {
    int b = blockIdx.x, t = threadIdx.x;
    __shared__ float vbuf[512];
    __shared__ int   ibuf[512];
    float val = -1e30f;
    if (t < NL * NL) {
        float num = 0.f;
        for (int ut = 0; ut < NUT; ++ut)
            num += ws[CCPART2 + ((size_t)(b * NUT + ut)) * 441 + t];
        float ls  = ws[LOCALSUM + b * (NL * NL) + t];
        float lsq = ws[LOCALSQ  + b * (NL * NL) + t];
        float ivar = lsq - ls * ls * (1.0f / N_T) + EPSF;
        if (ivar < 0.f) ivar = 0.f;
        float den = sqrtf(ws[TSTATS + 1] * ivar);
        float ncc = num / den;
        if (ncc != ncc) ncc = 0.f;
        val = ncc;
    }
    vbuf[t] = val; ibuf[t] = t;
    __syncthreads();
    for (int off = 256; off; off >>= 1) {
        if (t < off) {
            float v1 = vbuf[t], v2 = vbuf[t + off];
            int   i1 = ibuf[t], i2 = ibuf[t + off];
            if (v2 > v1 || (v2 == v1 && i2 < i1)) { vbuf[t] = v2; ibuf[t] = i2; }
        }
        __syncthreads();
    }
    if (t == 0) {
        int am = ibuf[0];
        ws[SHIFTSI + 2 * b]     = (float)(am / NL);
        ws[SHIFTSI + 2 * b + 1] = (float)(am % NL);
    }
}

// ---------------- K4b: exact fp32 NCC at 5 stencil points + subpixel (merged) ----------------
// One block per batch, 512 threads / 8 waves. All 5 numerators accumulated in one
// pass (r0 row feeds 3 points via L1-hot +/-1-column reads). Shifts computed inline.
__global__ __launch_bounds__(512) void k_exact(const float* __restrict__ x,
                                               const float* __restrict__ tpl,
                                               float* __restrict__ ws) {
    const int b = blockIdx.x;
    const int sx = (int)ws[SHIFTSI + 2 * b];
    const int sy = (int)ws[SHIFTSI + 2 * b + 1];
    const int lxm = max(sx - 1, 0), lxp = min(sx + 1, NL - 1);
    const int lym = max(sy - 1, 0), lyp = min(sy + 1, NL - 1);
    const float mu = ws[TSTATS];
    const int lane = threadIdx.x & 63, wv = threadIdx.x >> 6;   // 8 waves
    float a0 = 0.f, a1 = 0.f, a2 = 0.f, a3 = 0.f, a4 = 0.f;
    for (int t = wv; t < TN; t += 8) {
        const float* trow = tpl + (TOFF + t) * WW + TOFF;
        const float* r0 = x + ((size_t)b * HH + (CXY + sx  + t)) * WW + CXY;
        const float* r1 = x + ((size_t)b * HH + (CXY + lxm + t)) * WW + CXY;
        const float* r2 = x + ((size_t)b * HH + (CXY + lxp + t)) * WW + CXY;
#pragma unroll
        for (int it = 0; it < 6; ++it) {
            int v = lane + it * 64;
            if (v < TN) {
                float tz = trow[v] - mu;
                a0 = fmaf(tz, r0[sy  + v], a0);
                a1 = fmaf(tz, r1[sy  + v], a1);
                a2 = fmaf(tz, r2[sy  + v], a2);
                a3 = fmaf(tz, r0[lym + v], a3);
                a4 = fmaf(tz, r0[lyp + v], a4);
            }
        }
    }
    for (int off = 32; off; off >>= 1) {
        a0 += __shfl_down(a0, off); a1 += __shfl_down(a1, off);
        a2 += __shfl_down(a2, off); a3 += __shfl_down(a3, off);
        a4 += __shfl_down(a4, off);
    }
    __shared__ float red[8][5];
    if (lane == 0) {
        red[wv][0] = a0; red[wv][1] = a1; red[wv][2] = a2;
        red[wv][3] = a3; red[wv][4] = a4;
    }
    __syncthreads();
    if (threadIdx.x == 0) {
        float n[5];
        for (int k = 0; k < 5; ++k) {
            float s = 0.f;
            for (int w = 0; w < 8; ++w) s += red[w][k];
            n[k] = s;
        }
        const float tvar = ws[TSTATS + 1];
        const int cells[5] = { sx * NL + sy, lxm * NL + sy, lxp * NL + sy,
                               sx * NL + lym, sx * NL + lyp };
        float l[5];
        for (int k = 0; k < 5; ++k) {
            float ls  = ws[LOCALSUM + b * (NL * NL) + cells[k]];
            float lsq = ws[LOCALSQ  + b * (NL * NL) + cells[k]];
            float ivar = lsq - ls * ls * (1.0f / N_T) + EPSF;
            if (ivar < 0.f) ivar = 0.f;
            float ncc = n[k] / sqrtf(tvar * ivar);
            if (ncc != ncc) ncc = 0.f;
            l[k] = logf(ncc);
        }
        float shx = -(float)(sx - 10) - (l[1] - l[2]) / (2.f * l[1] - 4.f * l[0] + 2.f * l[2]);
        float shy = -(float)(sy - 10) - (l[3] - l[4]) / (2.f * l[3] - 4.f * l[0] + 2.f * l[4]);
        ws[SHIFTS + 2 * b]     = shx;
        ws[SHIFTS + 2 * b + 1] = shy;
    }
}

// ---------------- K5: bilinear warp, LDS-tiled (weights are const per batch) ----------------
__global__ __launch_bounds__(256) void k_warp(const float* __restrict__ x,
                                              const float* __restrict__ ws,
                                              float* __restrict__ out) {
    const int b = blockIdx.z;
    const int R = blockIdx.x * 64;     // output row tile
    const int C = blockIdx.y * 64;     // output col tile
    const float dy = ws[SHIFTS + 2 * b], dx = ws[SHIFTS + 2 * b + 1];
    const int rlo = (int)floorf((float)R - dy);
    const int clo = (int)floorf((float)C - dx);
    const float wr = ((float)R - dy) - (float)rlo;
    const float wc = ((float)C - dx) - (float)clo;
    __shared__ float sm[66][67];       // 66x66 staged tile, stride 67 (2-way free)
    const float* img = x + (size_t)b * (HH * WW);

    for (int k = threadIdx.x; k < 66 * 66; k += 256) {
        int kr = k / 66, kc = k - kr * 66;
        int ri = min(max(rlo + kr, 0), HH - 1);
        int ci = min(max(clo + kc, 0), WW - 1);
        sm[kr][kc] = img[ri * WW + ci];
    }
    __syncthreads();

    const int dr = threadIdx.x & 63;
    const int cq = threadIdx.x >> 6;     // 0..3
    const int r  = R + dr;
    const int r0 = rlo + dr;
    const float w00 = (1.f - wr) * (1.f - wc), w01 = (1.f - wr) * wc;
    const float w10 = wr * (1.f - wc),         w11 = wr * wc;
    const bool vr0 = (r0 >= 0) & (r0 < HH);
    const bool vr1 = (r0 + 1 >= 0) & (r0 + 1 < HH);
#pragma unroll
    for (int ci = 0; ci < 16; ++ci) {
        int dc = cq * 16 + ci;
        int c  = C + dc;
        int c0 = clo + dc;
        bool vc0 = (c0 >= 0) & (c0 < WW);
        bool vc1 = (c0 + 1 >= 0) & (c0 + 1 < WW);
        float v00 = (vr0 & vc0) ? sm[dr][dc]         : 0.f;
        float v01 = (vr0 & vc1) ? sm[dr][dc + 1]     : 0.f;
        float v10 = (vr1 & vc0) ? sm[dr + 1][dc]     : 0.f;
        float v11 = (vr1 & vc1) ? sm[dr + 1][dc + 1] : 0.f;
        float o = v00 * w00 + v01 * w01 + v10 * w10 + v11 * w11;
        out[(size_t)b * (HH * WW) + (size_t)c * HH + r] = o;
    }
}

extern "C" void kernel_launch(void* const* d_in, const int* in_sizes, int n_in,
                              void* d_out, int out_size, void* d_ws, size_t ws_size,
                              hipStream_t stream) {
    const float* x   = (const float*)d_in[0];
    const float* tpl = (const float*)d_in[1];
    float* out = (float*)d_out;
    float* ws  = (float*)d_ws;

    k_tstats1<<<TN, 128, 0, stream>>>(tpl, ws);
    k_tstats2<<<1, 512, 0, stream>>>(ws);
    k_tshift<<<dim3(384, NL), 256, 0, stream>>>(tpl, ws);
    k_rowsum<<<(NB * 416) / 4, 256, 0, stream>>>(x, ws);
    k_vert<<<dim3(NB, 2), 512, 0, stream>>>(ws);
    k_ccm<<<dim3(NB, NUT), 256, 0, stream>>>(ws);
    k_ncc<<<NB, 512, 0, stream>>>(ws);
    k_exact<<<NB, 512, 0, stream>>>(x, tpl, ws);
    k_warp<<<dim3(8, 8, NB), dim3(256), 0, stream>>>(x, ws, out);
}

// Round 13
// 147.584 us; speedup vs baseline: 1.1400x; 1.1400x over previous
//
#include <hip/hip_runtime.h>
#include <math.h>

// Problem constants
#define HH 512
#define WW 512
#define NB 64
#define CXY 56          // crop offset of Xc in x
#define TOFF 66         // crop offset of tmpl in template (MS+C = 10+56)
#define TN 380          // template side
#define XN 400          // cropped image side
#define NL 21           // number of lags per dim (XN-TN+1)
#define N_T 144400.0f   // TN*TN
#define EPSF 1e-8f
#define NUT 32          // u-tiles of 12 owned rows (32*12 = 384 >= 380)
#define SXS 424         // padded sX row stride in halfs (848 B)

// d_ws float offsets.  NOTE: CCPART2 aliases ROWSUM/ROWSUMSQ (dead after k_vert).
#define TPART_S   0                    // 380
#define TPART_S2  384                  // 380
#define TSTATS    768                  // [0]=mu_t [1]=t_var
#define ROWSUM    1024                 // 64*400*21 = 537600
#define ROWSUMSQ  (ROWSUM + 537600)    // 538624 (end 1076224)
#define CCPART2   1024                 // alias: 64*32*441 = 903168 (end 904192, fits)
#define LOCALSUM  1076224              // 64*441
#define LOCALSQ   (LOCALSUM + 28224)   // 1104448 (end 1132672)
#define SHIFTS    1132672              // final float shifts (128)
#define SHIFTSI   (SHIFTS + 128)       // integer argmax cells (128)
#define EXACTN    (SHIFTSI + 128)      // exact numerators, 5/batch (384)
#define TSHIFT_F  (EXACTN + 384)       // 1133312; f16 21*384*416 halfs (1677312 floats)
#define XF16      (TSHIFT_F + 1677312) // 2810624; f16 Xc 64*416*416 halfs (5537792 floats)
// end: 8348416 floats = 33.4 MB

typedef _Float16 half2_t __attribute__((ext_vector_type(2)));
typedef _Float16 f16x8 __attribute__((ext_vector_type(8)));
typedef float f32x4 __attribute__((ext_vector_type(4)));

// ---------------- K0a: per-template-row partial sums ----------------
__global__ __launch_bounds__(128) void k_tstats1(const float* __restrict__ tpl,
                                                 float* __restrict__ ws) {
    int u = blockIdx.x;            // 0..379
    int l = threadIdx.x;           // 128
    const float* row = tpl + (TOFF + u) * WW + TOFF;
    float s = 0.f, s2 = 0.f;
    for (int v = l; v < TN; v += 128) { float t = row[v]; s += t; s2 += t * t; }
    for (int off = 32; off; off >>= 1) { s += __shfl_down(s, off); s2 += __shfl_down(s2, off); }
    __shared__ float rs[2], rs2[2];
    int wid = l >> 6;
    if ((l & 63) == 0) { rs[wid] = s; rs2[wid] = s2; }
    __syncthreads();
    if (l == 0) { ws[TPART_S + u] = rs[0] + rs[1]; ws[TPART_S2 + u] = rs2[0] + rs2[1]; }
}

// ---------------- K0b: finalize template stats ----------------
__global__ __launch_bounds__(512) void k_tstats2(float* __restrict__ ws) {
    int l = threadIdx.x;           // 512
    float s  = (l < TN) ? ws[TPART_S + l]  : 0.f;
    float s2 = (l < TN) ? ws[TPART_S2 + l] : 0.f;
    for (int off = 32; off; off >>= 1) { s += __shfl_down(s, off); s2 += __shfl_down(s2, off); }
    __shared__ float rs[8], rs2[8];
    int wid = l >> 6;
    if ((l & 63) == 0) { rs[wid] = s; rs2[wid] = s2; }
    __syncthreads();
    if (l == 0) {
        float S = 0.f, S2 = 0.f;
        for (int k = 0; k < 8; ++k) { S += rs[k]; S2 += rs2[k]; }
        float mu = S / N_T;
        ws[TSTATS] = mu;
        ws[TSTATS + 1] = S2 - S * mu + EPSF;   // sum((T-mu)^2) + EPS
    }
}

// ---------------- K0c: build 21 shifted zero-mean f16 template copies ----------------
__global__ __launch_bounds__(256) void k_tshift(const float* __restrict__ tpl,
                                                float* __restrict__ ws) {
    int u = blockIdx.x;            // 0..383
    int j = blockIdx.y;            // 0..20
    float mu = ws[TSTATS];
    _Float16* dst = (_Float16*)(ws + TSHIFT_F) + ((size_t)j * 384 + u) * 416;
    for (int c = threadIdx.x; c < 416; c += 256) {
        float v = 0.f;
        int vs = c - j;
        if (u < TN && vs >= 0 && vs < TN) v = tpl[(TOFF + u) * WW + TOFF + vs] - mu;
        dst[c] = (_Float16)v;
    }
}

// ---------------- K1: sliding window sums + fused f32->f16 conversion ----------------
__global__ __launch_bounds__(256) void k_rowsum(const float* __restrict__ x,
                                                float* __restrict__ ws) {
    __shared__ float sm[4][416];
    int wid = threadIdx.x >> 6, lane = threadIdx.x & 63;
    int row = blockIdx.x * 4 + wid;        // 0..26623
    int b = row / 416, p = row - b * 416;  // p in [0,416)
    const float* xr = x + ((size_t)b * HH + (CXY + p)) * WW + CXY;
    _Float16* xh = (_Float16*)(ws + XF16) + ((size_t)b * 416 + p) * 416;
    float s = 0.f, s2 = 0.f;
    for (int v = lane; v < 416; v += 64) {
        float t = xr[v];
        sm[wid][v] = t;
        xh[v] = (_Float16)t;
        if (v < TN) { s += t; s2 += t * t; }
    }
    for (int off = 32; off; off >>= 1) { s += __shfl_down(s, off); s2 += __shfl_down(s2, off); }
    __syncthreads();
    if (lane == 0 && p < XN) {
        float* rs  = ws + ROWSUM   + (size_t)(b * XN + p) * NL;
        float* rq  = ws + ROWSUMSQ + (size_t)(b * XN + p) * NL;
        float w = s, w2 = s2;
        rs[0] = w; rq[0] = w2;
        for (int j = 1; j < NL; ++j) {
            float a = sm[wid][j - 1], bv = sm[wid][j + TN - 1];
            w  += bv - a;
            w2 += bv * bv - a * a;
            rs[j] = w; rq[j] = w2;
        }
    }
}

// ---------------- K2: vertical 380-tall sums (split sum/sumsq, padded LDS) ----------------
__global__ __launch_bounds__(512) void k_vert(float* __restrict__ ws) {
    int b = blockIdx.x, half = blockIdx.y, t = threadIdx.x;
    __shared__ float sm[XN * 22];   // padded stride 22 (2-way max)
    const float* src = ws + (half ? ROWSUMSQ : ROWSUM) + (size_t)b * (XN * NL);
    for (int k = t; k < XN * NL; k += 512) {
        int p = k / NL, j = k - p * NL;
        sm[p * 22 + j] = src[k];
    }
    __syncthreads();
    if (t < NL * NL) {
        int i = t / NL, j = t - i * NL;
        const float* base = sm + i * 22 + j;
        float s0 = 0.f, s1 = 0.f, s2 = 0.f, s3 = 0.f;
        for (int p = 0; p < TN; p += 4) {
            s0 += base[p * 22];
            s1 += base[(p + 1) * 22];
            s2 += base[(p + 2) * 22];
            s3 += base[(p + 3) * 22];
        }
        ws[(half ? LOCALSQ : LOCALSUM) + b * (NL * NL) + t] = (s0 + s1) + (s2 + s3);
    }
}

// ---------------- K3: MFMA cross-correlation (batch-paired, 3-j groups, ring-2) ----------------
// Block (bp, ut): batches b0=2bp, b1=2bp+1; owns u in [12ut,12ut+12); stages BOTH
// X tiles (rows [12ut,12ut+32) x 416 f16). Each A-fragment load feeds 4 MFMAs
// (2 n-tiles x 2 batches) -> A L2 traffic halves, arithmetic intensity doubles.
// LDS 63KB -> 2 blocks/CU; VGPR free up to ~256, audited ~100 live (no spill).
__global__ __launch_bounds__(256) void k_ccm(float* __restrict__ ws) {
    const int bp = blockIdx.x, ut = blockIdx.y;  // bp fastest: concurrent blocks share A-tile
    const int U = 12 * ut;
    const int tid = threadIdx.x;
    const int lane = tid & 63, wv = tid >> 6;
    __shared__ __align__(16) _Float16 sX[2][32 * SXS];  // 54272 B
    __shared__ float sD[4][16][34];                     // 8704 B -> 62976 total

    // ---- stage 2 x (32 rows x 416 halfs) from xh (16B chunks, coalesced) ----
    {
        const _Float16* xh = (const _Float16*)(ws + XF16);
#pragma unroll
        for (int bb = 0; bb < 2; ++bb) {
            const _Float16* src0 = xh + ((size_t)(2 * bp + bb) * 416 + U) * 416;
            for (int c = tid; c < 32 * 52; c += 256) {
                int r = c / 52, c8 = c - r * 52;
                *reinterpret_cast<f16x8*>(&sX[bb][r * SXS + c8 * 8]) =
                    *reinterpret_cast<const f16x8*>(src0 + (size_t)r * 416 + c8 * 8);
            }
        }
    }
    __syncthreads();

    const _Float16* tsh = (const _Float16*)(ws + TSHIFT_F);
    const int r16 = lane & 15, h8 = (lane >> 4) * 8;
    const int rbase = (lane >> 4) * 4, cbase = lane & 15;
    const _Float16* bbA = &sX[0][r16 * SXS + h8];
    const _Float16* bbB = &sX[1][r16 * SXS + h8];

    for (int gi = 0; gi < 2; ++gi) {
        const int g = wv + 4 * gi;
        if (g >= 7) break;                    // wave-uniform
        const int j0 = 3 * g;                 // j0, j0+1, j0+2 (7*3 = 21 exactly)
        const _Float16* a0 = tsh + ((size_t)(j0    ) * 384 + U + r16) * 416 + h8;
        const _Float16* a1 = tsh + ((size_t)(j0 + 1) * 384 + U + r16) * 416 + h8;
        const _Float16* a2 = tsh + ((size_t)(j0 + 2) * 384 + U + r16) * 416 + h8;

        f32x4 z = {0.f, 0.f, 0.f, 0.f};
        f32x4 c000 = z, c001 = z, c010 = z, c011 = z, c020 = z, c021 = z;  // batch 0
        f32x4 c100 = z, c101 = z, c110 = z, c111 = z, c120 = z, c121 = z;  // batch 1
        f16x8 A0 = *reinterpret_cast<const f16x8*>(a0);
        f16x8 A1 = *reinterpret_cast<const f16x8*>(a1);
        f16x8 A2 = *reinterpret_cast<const f16x8*>(a2);
#pragma unroll
        for (int kc = 0; kc < 13; ++kc) {
            f16x8 N0 = A0, N1 = A1, N2 = A2;
            if (kc < 12) {
                N0 = *reinterpret_cast<const f16x8*>(a0 + (kc + 1) * 32);
                N1 = *reinterpret_cast<const f16x8*>(a1 + (kc + 1) * 32);
                N2 = *reinterpret_cast<const f16x8*>(a2 + (kc + 1) * 32);
            }
            f16x8 B00 = *reinterpret_cast<const f16x8*>(bbA + kc * 32);
            f16x8 B01 = *reinterpret_cast<const f16x8*>(bbA + 16 * SXS + kc * 32);
            f16x8 B10 = *reinterpret_cast<const f16x8*>(bbB + kc * 32);
            f16x8 B11 = *reinterpret_cast<const f16x8*>(bbB + 16 * SXS + kc * 32);
            __builtin_amdgcn_s_setprio(1);
            c000 = __builtin_amdgcn_mfma_f32_16x16x32_f16(A0, B00, c000, 0, 0, 0);
            c001 = __builtin_amdgcn_mfma_f32_16x16x32_f16(A0, B01, c001, 0, 0, 0);
            c100 = __builtin_amdgcn_mfma_f32_16x16x32_f16(A0, B10, c100, 0, 0, 0);
            c101 = __builtin_amdgcn_mfma_f32_16x16x32_f16(A0, B11, c101, 0, 0, 0);
            c010 = __builtin_amdgcn_mfma_f32_16x16x32_f16(A1, B00, c010, 0, 0, 0);
            c011 = __builtin_amdgcn_mfma_f32_16x16x32_f16(A1, B01, c011, 0, 0, 0);
            c110 = __builtin_amdgcn_mfma_f32_16x16x32_f16(A1, B10, c110, 0, 0, 0);
            c111 = __builtin_amdgcn_mfma_f32_16x16x32_f16(A1, B11, c111, 0, 0, 0);
            c020 = __builtin_amdgcn_mfma_f32_16x16x32_f16(A2, B00, c020, 0, 0, 0);
            c021 = __builtin_amdgcn_mfma_f32_16x16x32_f16(A2, B01, c021, 0, 0, 0);
            c120 = __builtin_amdgcn_mfma_f32_16x16x32_f16(A2, B10, c120, 0, 0, 0);
            c121 = __builtin_amdgcn_mfma_f32_16x16x32_f16(A2, B11, c121, 0, 0, 0);
            __builtin_amdgcn_s_setprio(0);
            A0 = N0; A1 = N1; A2 = N2;
        }

        // ---- extract per (j, batch): s_i = sum_{row<12} D[row][row+i] ----
#pragma unroll
        for (int jj = 0; jj < 3; ++jj) {
#pragma unroll
            for (int bb = 0; bb < 2; ++bb) {
                f32x4 d0, d1;
                if (bb == 0) { d0 = (jj == 0) ? c000 : (jj == 1) ? c010 : c020;
                               d1 = (jj == 0) ? c001 : (jj == 1) ? c011 : c021; }
                else         { d0 = (jj == 0) ? c100 : (jj == 1) ? c110 : c120;
                               d1 = (jj == 0) ? c101 : (jj == 1) ? c111 : c121; }
#pragma unroll
                for (int q = 0; q < 4; ++q) {
                    sD[wv][rbase + q][cbase]      = d0[q];
                    sD[wv][rbase + q][16 + cbase] = d1[q];
                }
                if (lane < NL) {
                    float s = 0.f;
#pragma unroll
                    for (int row = 0; row < 12; ++row) s += sD[wv][row][row + lane];
                    ws[CCPART2 + ((size_t)((2 * bp + bb) * NUT + ut)) * 441
                       + lane * NL + (j0 + jj)] = s;
                }
            }
        }
    }
}

// ---------------- K4: NCC + argmax (first-index ties) -> integer cell ----------------
__global__ __launch_bounds__(512) void k_ncc(float* __restrict__ ws) {
    int b = blockIdx.x, t = threadIdx.x;
    __shared__ float vbuf[512];
    __shared__ int   ibuf[512];
    float val = -1e30f;
    if (t < NL * NL) {
        float num = 0.f;
        for (int ut = 0; ut < NUT; ++ut)
            num += ws[CCPART2 + ((size_t)(b * NUT + ut)) * 441 + t];
        float ls  = ws[LOCALSUM + b * (NL * NL) + t];
        float lsq = ws[LOCALSQ  + b * (NL * NL) + t];
        float ivar = lsq - ls * ls * (1.0f / N_T) + EPSF;
        if (ivar < 0.f) ivar = 0.f;
        float den = sqrtf(ws[TSTATS + 1] * ivar);
        float ncc = num / den;
        if (ncc != ncc) ncc = 0.f;
        val = ncc;
    }
    vbuf[t] = val; ibuf[t] = t;
    __syncthreads();
    for (int off = 256; off; off >>= 1) {
        if (t < off) {
            float v1 = vbuf[t], v2 = vbuf[t + off];
            int   i1 = ibuf[t], i2 = ibuf[t + off];
            if (v2 > v1 || (v2 == v1 && i2 < i1)) { vbuf[t] = v2; ibuf[t] = i2; }
        }
        __syncthreads();
    }
    if (t == 0) {
        int am = ibuf[0];
        ws[SHIFTSI + 2 * b]     = (float)(am / NL);
        ws[SHIFTSI + 2 * b + 1] = (float)(am % NL);
    }
}

// ---------------- K4b: exact fp32 numerators at the 5 stencil points ----------------
__global__ __launch_bounds__(512) void k_exact1(const float* __restrict__ x,
                                                const float* __restrict__ tpl,
                                                float* __restrict__ ws) {
    const int b = blockIdx.x, k = blockIdx.y;
    const int sx = (int)ws[SHIFTSI + 2 * b];
    const int sy = (int)ws[SHIFTSI + 2 * b + 1];
    const int dxs[5] = {0, -1, 1, 0, 0};
    const int dys[5] = {0, 0, 0, -1, 1};
    const int px = min(max(sx + dxs[k], 0), NL - 1);
    const int py = min(max(sy + dys[k], 0), NL - 1);
    const float mu = ws[TSTATS];
    const int lane = threadIdx.x & 63, wv = threadIdx.x >> 6;   // 8 waves
    float a = 0.f;
    for (int t = wv; t < TN; t += 8) {
        const float* trow = tpl + (TOFF + t) * WW + TOFF;
        const float* xrow = x + ((size_t)b * HH + (CXY + px + t)) * WW + CXY + py;
#pragma unroll
        for (int it = 0; it < 6; ++it) {
            int v = lane + it * 64;
            if (v < TN) a = fmaf(trow[v] - mu, xrow[v], a);
        }
    }
    for (int off = 32; off; off >>= 1) a += __shfl_down(a, off);
    __shared__ float part[8];
    if (lane == 0) part[wv] = a;
    __syncthreads();
    if (threadIdx.x == 0) {
        float s = 0.f;
        for (int w = 0; w < 8; ++w) s += part[w];
        ws[EXACTN + b * 5 + k] = s;
    }
}

// ---------------- K4c: subpixel shifts from exact numerators ----------------
__global__ __launch_bounds__(64) void k_sub(float* __restrict__ ws) {
    int b = threadIdx.x;
    if (b >= NB) return;
    int sx = (int)ws[SHIFTSI + 2 * b];
    int sy = (int)ws[SHIFTSI + 2 * b + 1];
    int lxm = max(sx - 1, 0), lxp = min(sx + 1, NL - 1);
    int lym = max(sy - 1, 0), lyp = min(sy + 1, NL - 1);
    float tvar = ws[TSTATS + 1];
    int cells[5] = { sx * NL + sy, lxm * NL + sy, lxp * NL + sy,
                     sx * NL + lym, sx * NL + lyp };
    float l[5];
    for (int k = 0; k < 5; ++k) {
        float num = ws[EXACTN + b * 5 + k];
        float ls  = ws[LOCALSUM + b * (NL * NL) + cells[k]];
        float lsq = ws[LOCALSQ  + b * (NL * NL) + cells[k]];
        float ivar = lsq - ls * ls * (1.0f / N_T) + EPSF;
        if (ivar < 0.f) ivar = 0.f;
        float ncc = num / sqrtf(tvar * ivar);
        if (ncc != ncc) ncc = 0.f;
        l[k] = logf(ncc);
    }
    float shx = -(float)(sx - 10) - (l[1] - l[2]) / (2.f * l[1] - 4.f * l[0] + 2.f * l[2]);
    float shy = -(float)(sy - 10) - (l[3] - l[4]) / (2.f * l[3] - 4.f * l[0] + 2.f * l[4]);
    ws[SHIFTS + 2 * b]     = shx;
    ws[SHIFTS + 2 * b + 1] = shy;
}

// ---------------- K5: bilinear warp, LDS-tiled (weights are const per batch) ----------------
__global__ __launch_bounds__(256) void k_warp(const float* __restrict__ x,
                                              const float* __restrict__ ws,
                                              float* __restrict__ out) {
    const int b = blockIdx.z;
    const int R = blockIdx.x * 64;     // output row tile
    const int C = blockIdx.y * 64;     // output col tile
    const float dy = ws[SHIFTS + 2 * b], dx = ws[SHIFTS + 2 * b + 1];
    const int rlo = (int)floorf((float)R - dy);
    const int clo = (int)floorf((float)C - dx);
    const float wr = ((float)R - dy) - (float)rlo;
    const float wc = ((float)C - dx) - (float)clo;
    __shared__ float sm[66][67];       // 66x66 staged tile, stride 67 (2-way free)
    const float* img = x + (size_t)b * (HH * WW);

    for (int k = threadIdx.x; k < 66 * 66; k += 256) {
        int kr = k / 66, kc = k - kr * 66;
        int ri = min(max(rlo + kr, 0), HH - 1);
        int ci = min(max(clo + kc, 0), WW - 1);
        sm[kr][kc] = img[ri * WW + ci];
    }
    __syncthreads();

    const int dr = threadIdx.x & 63;
    const int cq = threadIdx.x >> 6;     // 0..3
    const int r  = R + dr;
    const int r0 = rlo + dr;
    const float w00 = (1.f - wr) * (1.f - wc), w01 = (1.f - wr) * wc;
    const float w10 = wr * (1.f - wc),         w11 = wr * wc;
    const bool vr0 = (r0 >= 0) & (r0 < HH);
    const bool vr1 = (r0 + 1 >= 0) & (r0 + 1 < HH);
#pragma unroll
    for (int ci = 0; ci < 16; ++ci) {
        int dc = cq * 16 + ci;
        int c  = C + dc;
        int c0 = clo + dc;
        bool vc0 = (c0 >= 0) & (c0 < WW);
        bool vc1 = (c0 + 1 >= 0) & (c0 + 1 < WW);
        float v00 = (vr0 & vc0) ? sm[dr][dc]         : 0.f;
        float v01 = (vr0 & vc1) ? sm[dr][dc + 1]     : 0.f;
        float v10 = (vr1 & vc0) ? sm[dr + 1][dc]     : 0.f;
        float v11 = (vr1 & vc1) ? sm[dr + 1][dc + 1] : 0.f;
        float o = v00 * w00 + v01 * w01 + v10 * w10 + v11 * w11;
        out[(size_t)b * (HH * WW) + (size_t)c * HH + r] = o;
    }
}

extern "C" void kernel_launch(void* const* d_in, const int* in_sizes, int n_in,
                              void* d_out, int out_size, void* d_ws, size_t ws_size,
                              hipStream_t stream) {
    const float* x   = (const float*)d_in[0];
    const float* tpl = (const float*)d_in[1];
    float* out = (float*)d_out;
    float* ws  = (float*)d_ws;

    k_tstats1<<<TN, 128, 0, stream>>>(tpl, ws);
    k_tstats2<<<1, 512, 0, stream>>>(ws);
    k_tshift<<<dim3(384, NL), 256, 0, stream>>>(tpl, ws);
    k_rowsum<<<(NB * 416) / 4, 256, 0, stream>>>(x, ws);
    k_vert<<<dim3(NB, 2), 512, 0, stream>>>(ws);
    k_ccm<<<dim3(NB / 2, NUT), 256, 0, stream>>>(ws);
    k_ncc<<<NB, 512, 0, stream>>>(ws);
    k_exact1<<<dim3(NB, 5), 512, 0, stream>>>(x, tpl, ws);
    k_sub<<<1, 64, 0, stream>>>(ws);
    k_warp<<<dim3(8, 8, NB), dim3(256), 0, stream>>>(x, ws, out);
}